// Round 6
// baseline (108.295 us; speedup 1.0000x reference)
//
#include <hip/hip_runtime.h>
#include <math.h>

#define N 4096
#define B 2048
#define RANK 4
#define ALPHA 0.8862269254527580f   // sqrt(pi)/2
#define INV_N (1.0f / 4096.0f)

#define NSPLIT 16                   // partial splits (256 rows each)
#define CSTRIPES 16                 // col-stripes of 128
#define PLANE (5 * B)               // one split = [5][B] floats
// grid: 16 row-groups x 16 col-stripes = 256 blocks x 1024 thr
//   -> 1 block/CU (80 KB LDS), 16 waves/CU; 256 blocks always co-resident
//   -> deadlock-free last-arrival protocol (reducer never waits).

typedef float vf4 __attribute__((ext_vector_type(4)));

// Branchless Winitzki erf (max abs err ~2.5e-4; threshold is 0.24).
__device__ __forceinline__ float erf_fast(float t) {
  const float A = 0.140012288f;
  const float FP = 1.2732395447f;  // 4/pi
  float t2 = t * t;
  float num = fmaf(A, t2, FP);
  float den = fmaf(A, t2, 1.0f);
  float r = t2 * num * __builtin_amdgcn_rcpf(den);
  float e = __expf(-r);
  float s = __builtin_amdgcn_sqrtf(fmaxf(1.0f - e, 0.0f));
  return copysignf(s, t);
}

// Agent-scope (LLC coherence point) access, NO fences: relaxed atomic
// load/store compile to global_load/store ... sc0 sc1 (read-through /
// write-through past the non-coherent per-XCD L2). Visibility protocol:
// sc1 stores -> __syncthreads (drains vmcnt(0)) -> device-scope ticket RMW.
// This is the fence-free replacement for R4's __threadfence() L2-flush storm.
__device__ __forceinline__ void cstore(float* p, float v) {
  __hip_atomic_store(p, v, __ATOMIC_RELAXED, __HIP_MEMORY_SCOPE_AGENT);
}
__device__ __forceinline__ float cload(const float* p) {
  return __hip_atomic_load(p, __ATOMIC_RELAXED, __HIP_MEMORY_SCOPE_AGENT);
}

// ---------------------------------------------------------------------------
// Single fused kernel.
// Phase 1: phi + rank-4(+z) partial reduce over 256-row x 128-col tile,
//          16-wave LDS tree -> 640 sc1 scalar stores (partials[16][5][B]).
// Ticket:  16th-arriving block per col-stripe folds 16 splits (10 indep sc1
//          loads/thread, ~one LLC latency round) -> sfin (sc1) + y; sets flag.
// Others:  lane-0 s_sleep spin on flag[cs] (one LLC line per stripe).
// Phase 2: h_new = (u @ sfin)/N + m x  (DT/TAU=1 -> h cancels), nontemporal
//          vf4 stores, same tile/addressing as phase 1.
// ---------------------------------------------------------------------------
__global__ __launch_bounds__(1024) void k_fused(
    const float* __restrict__ h, const float* __restrict__ v,
    const float* __restrict__ z, const float* __restrict__ u,
    const float* __restrict__ m, const float* __restrict__ x,
    float* __restrict__ partials, float* __restrict__ sfin,
    unsigned int* __restrict__ cnt, unsigned int* __restrict__ flag,
    float* __restrict__ y, float* __restrict__ hnew) {
  __shared__ __align__(16) float red[5][16][2][128];  // 80 KB
  __shared__ unsigned int sticket;
  const int tid = threadIdx.x;
  const int l = tid & 63;
  const int w = tid >> 6;            // wave, 0..15
  const int rg = blockIdx.x >> 4;    // row-group, 0..15
  const int cs = blockIdx.x & 15;    // col-stripe, 0..15
  const int hf = l >> 5;             // row-half within pair
  const int lc = (l & 31) * 4;       // col offset within stripe
  const int c0 = cs * 128;
  const int rbase = rg * 256 + w * 16 + hf;  // this lane's first row

  // ---- Phase 1: phi + rank-4(+z) partial reduction ------------------------
  vf4 a0 = {0.f, 0.f, 0.f, 0.f};
  vf4 a1 = a0, a2 = a0, a3 = a0, a4 = a0;

  const float* hp = h + (size_t)rbase * B + c0 + lc;
#pragma unroll
  for (int i = 0; i < 8; ++i) {      // 8 row-pairs = 16 rows per wave
    const int row = rbase + 2 * i;
    const vf4 hv = *(const vf4*)(hp + (size_t)(2 * i) * B);
    const vf4 vv = *(const vf4*)(v + (size_t)row * RANK);  // half-wave shared
    const float zr = z[row];
    vf4 p;
    p.x = erf_fast(ALPHA * hv.x);
    p.y = erf_fast(ALPHA * hv.y);
    p.z = erf_fast(ALPHA * hv.z);
    p.w = erf_fast(ALPHA * hv.w);
    a0.x = fmaf(vv.x, p.x, a0.x); a0.y = fmaf(vv.x, p.y, a0.y);
    a0.z = fmaf(vv.x, p.z, a0.z); a0.w = fmaf(vv.x, p.w, a0.w);
    a1.x = fmaf(vv.y, p.x, a1.x); a1.y = fmaf(vv.y, p.y, a1.y);
    a1.z = fmaf(vv.y, p.z, a1.z); a1.w = fmaf(vv.y, p.w, a1.w);
    a2.x = fmaf(vv.z, p.x, a2.x); a2.y = fmaf(vv.z, p.y, a2.y);
    a2.z = fmaf(vv.z, p.z, a2.z); a2.w = fmaf(vv.z, p.w, a2.w);
    a3.x = fmaf(vv.w, p.x, a3.x); a3.y = fmaf(vv.w, p.y, a3.y);
    a3.z = fmaf(vv.w, p.z, a3.z); a3.w = fmaf(vv.w, p.w, a3.w);
    a4.x = fmaf(zr, p.x, a4.x); a4.y = fmaf(zr, p.y, a4.y);
    a4.z = fmaf(zr, p.z, a4.z); a4.w = fmaf(zr, p.w, a4.w);
  }

  // LDS tree deposit (conflict-free: 16 B/lane, consecutive).
  *(vf4*)&red[0][w][hf][lc] = a0;
  *(vf4*)&red[1][w][hf][lc] = a1;
  *(vf4*)&red[2][w][hf][lc] = a2;
  *(vf4*)&red[3][w][hf][lc] = a3;
  *(vf4*)&red[4][w][hf][lc] = a4;
  __syncthreads();

  // 5 planes x 128 cols = 640 outputs; 32-way sum; sc1 write-through store.
  if (tid < 5 * 128) {
    const int p = tid >> 7;
    const int c = tid & 127;
    float s = 0.f;
#pragma unroll
    for (int w2 = 0; w2 < 16; ++w2) {
      s += red[p][w2][0][c];
      s += red[p][w2][1][c];
    }
    cstore(&partials[(size_t)rg * PLANE + p * B + c0 + c], s);
  }
  __syncthreads();                   // drains vmcnt(0): sc1 stores at LLC

  // ---- Ticket: last arrival in stripe cs does the fold --------------------
  if (tid == 0) sticket = atomicAdd(&cnt[cs], 1u);  // device-scope RMW @ LLC
  __syncthreads();
  const bool isred = (sticket == NSPLIT - 1);

  if (isred && tid < 5 * 128) {
    const int p = tid >> 7;
    const int c = tid & 127;
    const float* pp = &partials[(size_t)p * B + c0 + c];
    float s = 0.f;
#pragma unroll
    for (int sp = 0; sp < NSPLIT; ++sp)   // 16 independent sc1 loads
      s += cload(pp + (size_t)sp * PLANE);
    if (p < RANK)
      cstore(&sfin[p * B + c0 + c], s);
    else
      y[c0 + c] = s * INV_N;         // y = (z.T @ phi) / N (plain store, host-read)
  }
  __syncthreads();                   // drains reducer's sfin sc1 stores

  if (isred) {
    if (tid == 0)
      __hip_atomic_store(&flag[cs], 1u, __ATOMIC_RELAXED,
                         __HIP_MEMORY_SCOPE_AGENT);
  } else {
    if (tid == 0) {
      while (__hip_atomic_load(&flag[cs], __ATOMIC_RELAXED,
                               __HIP_MEMORY_SCOPE_AGENT) == 0u)
        __builtin_amdgcn_s_sleep(4);
    }
  }
  __syncthreads();                   // broadcast "sfin ready" to whole block

  // ---- Phase 2: h_new[n][b] = (sum_r u[n][r]*sfin[r][b])/N + m[n]*x[b] ----
  // 16 independent sc1 scalar loads rebuild s0..s3 (LLC-hit, one round).
  vf4 s0, s1, s2, s3;
#define LD4(d, p)                              \
  d.x = cload(&sfin[(p) * B + c0 + lc + 0]);   \
  d.y = cload(&sfin[(p) * B + c0 + lc + 1]);   \
  d.z = cload(&sfin[(p) * B + c0 + lc + 2]);   \
  d.w = cload(&sfin[(p) * B + c0 + lc + 3]);
  LD4(s0, 0) LD4(s1, 1) LD4(s2, 2) LD4(s3, 3)
#undef LD4
  const vf4 xa = *(const vf4*)(x + c0 + lc);

  float* op = hnew + (size_t)rbase * B + c0 + lc;
#pragma unroll
  for (int i = 0; i < 8; ++i) {
    const int row = rbase + 2 * i;   // per-half-wave, NOT wave-uniform
    const vf4 uv = *(const vf4*)(u + (size_t)row * RANK);
    const float mv = m[row];
    vf4 o;
    o.x = fmaf(mv, xa.x,
               (s0.x * uv.x + s1.x * uv.y + s2.x * uv.z + s3.x * uv.w) * INV_N);
    o.y = fmaf(mv, xa.y,
               (s0.y * uv.x + s1.y * uv.y + s2.y * uv.z + s3.y * uv.w) * INV_N);
    o.z = fmaf(mv, xa.z,
               (s0.z * uv.x + s1.z * uv.y + s2.z * uv.z + s3.z * uv.w) * INV_N);
    o.w = fmaf(mv, xa.w,
               (s0.w * uv.x + s1.w * uv.y + s2.w * uv.z + s3.w * uv.w) * INV_N);
    __builtin_nontemporal_store(o, (vf4*)(op + (size_t)(2 * i) * B));
  }
}

// ---------------------------------------------------------------------------
extern "C" void kernel_launch(void* const* d_in, const int* in_sizes, int n_in,
                              void* d_out, int out_size, void* d_ws,
                              size_t ws_size, hipStream_t stream) {
  const float* x = (const float*)d_in[0];  // [1, B]
  const float* h = (const float*)d_in[1];  // [N, B]
  const float* m = (const float*)d_in[2];  // [N, 1]
  const float* u = (const float*)d_in[3];  // [N, RANK]
  const float* v = (const float*)d_in[4];  // [N, RANK]
  const float* z = (const float*)d_in[5];  // [N, 1]

  float* y = (float*)d_out;            // output 0: y [1, B]
  float* hnew = (float*)d_out + B;     // output 1: h_new [N, B]

  float* partials = (float*)d_ws;                    // [16][5][B] fp32, 655 KB
  float* sfin = partials + (size_t)NSPLIT * PLANE;   // [RANK][B] fp32, 32 KB
  unsigned int* cnt = (unsigned int*)(sfin + RANK * B);   // [16] tickets
  unsigned int* flag = cnt + CSTRIPES;                    // [16] ready flags

  // Workspace is poisoned each iteration -> re-zero tickets+flags (128 B).
  hipMemsetAsync(cnt, 0, 2 * CSTRIPES * sizeof(unsigned int), stream);
  k_fused<<<NSPLIT * CSTRIPES, 1024, 0, stream>>>(h, v, z, u, m, x, partials,
                                                  sfin, cnt, flag, y, hnew);
}

// Round 7
// 102.553 us; speedup vs baseline: 1.0560x; 1.0560x over previous
//
#include <hip/hip_runtime.h>
#include <math.h>

#define N 4096
#define B 2048
#define RANK 4
#define ALPHA 0.8862269254527580f   // sqrt(pi)/2
#define INV_N (1.0f / 4096.0f)

#define NSPLIT 16                   // partial splits (256 rows each)
#define PLANE (5 * B)               // one split = [5][B] floats
// k1 grid: 16 row-groups x 16 col-stripes = 256 blocks x 1024 thr
//   -> 1 block/CU x 16 waves = 16 waves/CU
// k2 grid: 64 row-groups x 8 col-stripes = 512 blocks x 512 thr
// NOTE (session ledger): all four cross-block-sync mechanisms measured SLOWER
// than the plain stream boundary: fp32 global atomics (R1: 16B write-through
// each + per-address RMW serialization), cooperative launch (R3: graph-capture
// incompatible, silent no-launch), per-wave __threadfence (R4: L2-flush storm,
// 100us), sc1+ticket fusion (R6: +7us from scalar write-through stores, spin
// skew, extra memset dispatch). Two stream-ordered kernels is the optimum.

typedef float vf4 __attribute__((ext_vector_type(4)));

// Branchless Winitzki erf (max abs err ~2.5e-4; threshold is 0.24).
__device__ __forceinline__ float erf_fast(float t) {
  const float A = 0.140012288f;
  const float FP = 1.2732395447f;  // 4/pi
  float t2 = t * t;
  float num = fmaf(A, t2, FP);
  float den = fmaf(A, t2, 1.0f);
  float r = t2 * num * __builtin_amdgcn_rcpf(den);
  float e = __expf(-r);
  float s = __builtin_amdgcn_sqrtf(fmaxf(1.0f - e, 0.0f));
  return copysignf(s, t);
}

// ---------------------------------------------------------------------------
// Kernel 1: phi + rank-4(+z) partial reduction -> partials[16][5][B].
// 256 blocks (16 rg x 16 cs) x 1024 thr. Block owns 256 rows x 128 cols.
// Wave w owns 16 rows; lanes split: hf = l>>5 picks odd/even row of a pair,
// (l&31) picks the vf4 column -> each load inst covers 2 rows x 512 B
// contiguous. h loads are nontemporal (read-exactly-once; keep L2 for
// partials). 16-wave LDS tree (80 KB) -> 655 KB of global partials.
// ---------------------------------------------------------------------------
__global__ __launch_bounds__(1024) void k_phi_part(
    const float* __restrict__ h, const float* __restrict__ v,
    const float* __restrict__ z, float* __restrict__ partials) {
  __shared__ __align__(16) float red[5][16][2][128];  // 80 KB
  const int tid = threadIdx.x;
  const int l = tid & 63;
  const int w = tid >> 6;            // wave, 0..15
  const int rg = blockIdx.x >> 4;    // row-group, 0..15
  const int cs = blockIdx.x & 15;    // col-stripe, 0..15
  const int hf = l >> 5;             // row-half within pair
  const int lc = (l & 31) * 4;       // col offset within stripe
  const int c0 = cs * 128;
  const int rbase = rg * 256 + w * 16 + hf;  // this lane's first row

  vf4 a0 = {0.f, 0.f, 0.f, 0.f};
  vf4 a1 = a0, a2 = a0, a3 = a0, a4 = a0;

  const float* hp = h + (size_t)rbase * B + c0 + lc;
#pragma unroll
  for (int i = 0; i < 8; ++i) {      // 8 row-pairs = 16 rows per wave
    const int row = rbase + 2 * i;
    const vf4 hv = __builtin_nontemporal_load((const vf4*)(hp + (size_t)(2 * i) * B));
    const vf4 vv = *(const vf4*)(v + (size_t)row * RANK);  // half-wave shared
    const float zr = z[row];
    vf4 p;
    p.x = erf_fast(ALPHA * hv.x);
    p.y = erf_fast(ALPHA * hv.y);
    p.z = erf_fast(ALPHA * hv.z);
    p.w = erf_fast(ALPHA * hv.w);
    a0.x = fmaf(vv.x, p.x, a0.x); a0.y = fmaf(vv.x, p.y, a0.y);
    a0.z = fmaf(vv.x, p.z, a0.z); a0.w = fmaf(vv.x, p.w, a0.w);
    a1.x = fmaf(vv.y, p.x, a1.x); a1.y = fmaf(vv.y, p.y, a1.y);
    a1.z = fmaf(vv.y, p.z, a1.z); a1.w = fmaf(vv.y, p.w, a1.w);
    a2.x = fmaf(vv.z, p.x, a2.x); a2.y = fmaf(vv.z, p.y, a2.y);
    a2.z = fmaf(vv.z, p.z, a2.z); a2.w = fmaf(vv.z, p.w, a2.w);
    a3.x = fmaf(vv.w, p.x, a3.x); a3.y = fmaf(vv.w, p.y, a3.y);
    a3.z = fmaf(vv.w, p.z, a3.z); a3.w = fmaf(vv.w, p.w, a3.w);
    a4.x = fmaf(zr, p.x, a4.x); a4.y = fmaf(zr, p.y, a4.y);
    a4.z = fmaf(zr, p.z, a4.z); a4.w = fmaf(zr, p.w, a4.w);
  }

  // LDS tree deposit (conflict-free: 16 B/lane, consecutive).
  *(vf4*)&red[0][w][hf][lc] = a0;
  *(vf4*)&red[1][w][hf][lc] = a1;
  *(vf4*)&red[2][w][hf][lc] = a2;
  *(vf4*)&red[3][w][hf][lc] = a3;
  *(vf4*)&red[4][w][hf][lc] = a4;
  __syncthreads();

  // 5 planes x 128 cols = 640 outputs; 32-way sum each.
  if (tid < 5 * 128) {
    const int p = tid >> 7;
    const int c = tid & 127;
    float s = 0.f;
#pragma unroll
    for (int w2 = 0; w2 < 16; ++w2) {
      s += red[p][w2][0][c];
      s += red[p][w2][1][c];
    }
    partials[(size_t)rg * PLANE + p * B + c0 + c] = s;
  }
}

// ---------------------------------------------------------------------------
// Kernel 2: fold 16 splits (64 KB L2 reads/block, ~1 us/CU) then write h_new.
// 512 blocks (64 rg x 8 cs) x 512 thr; block owns 64 rows x 256 cols.
// Phase A: thread (p, hf, cv) sums 8 splits of plane p, cols cv -> LDS.
// rg==0 blocks also fold plane 4 -> y. Phase B: wave g writes its 8 rows
// as 1 KB contiguous nontemporal stores using the LDS sums + u/m scalars.
// (DT/TAU = 1 -> h cancels exactly; h is never read here.)
// ---------------------------------------------------------------------------
__global__ __launch_bounds__(512) void k_red_update(
    const float* __restrict__ partials, const float* __restrict__ u,
    const float* __restrict__ m, const float* __restrict__ x,
    float* __restrict__ y, float* __restrict__ hnew) {
  __shared__ __align__(16) float redA[4][2][256];  // 8 KB
  __shared__ __align__(16) float redY[2][256];     // 2 KB
  const int tid = threadIdx.x;
  const int rg = blockIdx.x >> 3;   // row-group, 0..63
  const int cs = blockIdx.x & 7;    // col-stripe, 0..7
  const int c0 = cs * 256;

  // ---- Phase A: planes 0..3, 16 splits -> redA[4][2][256] -----------------
  {
    const int p = tid >> 7;          // plane 0..3
    const int rem = tid & 127;
    const int hf = rem >> 6;         // split-half 0..1
    const int cv = (rem & 63) * 4;   // vf4 col offset
    const float* pp = partials + (size_t)(hf * 8) * PLANE + p * B + c0 + cv;
    vf4 sA = {0.f, 0.f, 0.f, 0.f};
    vf4 sB = sA;
#pragma unroll
    for (int sp = 0; sp < 8; sp += 2) {
      sA += *(const vf4*)(pp + (size_t)sp * PLANE);
      sB += *(const vf4*)(pp + (size_t)(sp + 1) * PLANE);
    }
    sA += sB;
    *(vf4*)&redA[p][hf][cv] = sA;
  }
  // ---- Phase A': plane 4 (y) for rg==0 blocks -----------------------------
  if (rg == 0 && tid < 128) {
    const int hf = tid >> 6;
    const int cv = (tid & 63) * 4;
    const float* pp = partials + (size_t)(hf * 8) * PLANE + 4 * B + c0 + cv;
    vf4 s = {0.f, 0.f, 0.f, 0.f};
#pragma unroll
    for (int sp = 0; sp < 8; ++sp)
      s += *(const vf4*)(pp + (size_t)sp * PLANE);
    *(vf4*)&redY[hf][cv] = s;
  }
  __syncthreads();

  if (rg == 0 && tid < 64) {
    vf4 yy = *(const vf4*)&redY[0][tid * 4] + *(const vf4*)&redY[1][tid * 4];
    yy *= INV_N;                     // y = (z.T @ phi) / N
    *(vf4*)(y + c0 + tid * 4) = yy;
  }

  // ---- Phase B: h_new[n][b] = (sum_r u[n][r]*s_r[b])/N + m[n]*x[b] --------
  const int g = tid >> 6;            // wave, 0..7
  const int l = tid & 63;
  const int lc = l * 4;
  const vf4 s0 = *(const vf4*)&redA[0][0][lc] + *(const vf4*)&redA[0][1][lc];
  const vf4 s1 = *(const vf4*)&redA[1][0][lc] + *(const vf4*)&redA[1][1][lc];
  const vf4 s2 = *(const vf4*)&redA[2][0][lc] + *(const vf4*)&redA[2][1][lc];
  const vf4 s3 = *(const vf4*)&redA[3][0][lc] + *(const vf4*)&redA[3][1][lc];
  const vf4 xa = *(const vf4*)(x + c0 + lc);

  const int r0 = rg * 64 + g * 8;
  float* op = hnew + (size_t)r0 * B + c0 + lc;
#pragma unroll
  for (int r = 0; r < 8; ++r) {
    const int row = __builtin_amdgcn_readfirstlane(r0 + r);  // wave-uniform
    const vf4 uv = *(const vf4*)(u + (size_t)row * RANK);
    const float mv = m[row];
    vf4 o;
    o.x = fmaf(mv, xa.x,
               (s0.x * uv.x + s1.x * uv.y + s2.x * uv.z + s3.x * uv.w) * INV_N);
    o.y = fmaf(mv, xa.y,
               (s0.y * uv.x + s1.y * uv.y + s2.y * uv.z + s3.y * uv.w) * INV_N);
    o.z = fmaf(mv, xa.z,
               (s0.z * uv.x + s1.z * uv.y + s2.z * uv.z + s3.z * uv.w) * INV_N);
    o.w = fmaf(mv, xa.w,
               (s0.w * uv.x + s1.w * uv.y + s2.w * uv.z + s3.w * uv.w) * INV_N);
    __builtin_nontemporal_store(o, (vf4*)(op + (size_t)r * B));
  }
}

// ---------------------------------------------------------------------------
extern "C" void kernel_launch(void* const* d_in, const int* in_sizes, int n_in,
                              void* d_out, int out_size, void* d_ws,
                              size_t ws_size, hipStream_t stream) {
  const float* x = (const float*)d_in[0];  // [1, B]
  const float* h = (const float*)d_in[1];  // [N, B]
  const float* m = (const float*)d_in[2];  // [N, 1]
  const float* u = (const float*)d_in[3];  // [N, RANK]
  const float* v = (const float*)d_in[4];  // [N, RANK]
  const float* z = (const float*)d_in[5];  // [N, 1]

  float* y = (float*)d_out;            // output 0: y [1, B]
  float* hnew = (float*)d_out + B;     // output 1: h_new [N, B]

  float* partials = (float*)d_ws;      // [16][5][B] fp32, 655 KB

  k_phi_part<<<256, 1024, 0, stream>>>(h, v, z, partials);
  k_red_update<<<512, 512, 0, stream>>>(partials, u, m, x, y, hnew);
}